// Round 17
// baseline (263.059 us; speedup 1.0000x reference)
//
#include <hip/hip_runtime.h>
#include <hip/hip_fp16.h>

#define HF 32
#define EPS 1e-5f
#define BSH 6
#define BSZ 64           // nodes per bucket
#define CH  16384        // edges per binning block (chunk-local sorted output)
#define CAP 2560         // bucket segment capacity in ep2 (mean 1600 + 8.5 sigma)
#define FXS 524288.0f    // 2^19 fixed-point scale (range +-4096, quant 1.9e-6)
#define FXI (1.0f/524288.0f)

typedef int vi4 __attribute__((ext_vector_type(4)));

__device__ __forceinline__ float leaky(float v){ return fmaxf(v, 0.01f*v); }
__device__ __forceinline__ float elu1(float v){ return v > 0.f ? v : (expf(v)-1.f); }
__device__ __forceinline__ float sigmoidf(float v){ return 1.f/(1.f+expf(-v)); }

// LESSONS: nt stores on scattered writes -> 143MB writeback. Scattered
// global atomics -> +84MB (r1). Degree-sorted NODE order -> imbalance (r2).
// FP atomics into LDS (any spelling) -> flat/CAS, 10-30x (r4/r6).
// Persistent kernel + grid barriers -> L2 flush (r7). INT LDS atomics
// fast -> Q.19 accumulation (r9). Gathers TLP/DS/MLP-insensitive
// (r10/r11/r12). Rank-capture binning -6us (r13). SRC counting-sort ->
// -10us (r14, 259us BEST). Unified bin+MLP -> write amp 3x, REJECTED
// (r15): binning is scatter-store-transaction bound. nt ep loads neutral
// (r16). THIS ROUND: chunk-local bucket-sorted binning output (all writes
// coalesced in the block's own 64KB window, amp -> 1.0) + offs[c][b]
// table; deg_t1 gathers 153 runs/bucket (thread-per-run). gfill gone.
__device__ __forceinline__ int4 nt_load_i4(const int* p){
    vi4 v = __builtin_nontemporal_load((const vi4*)p);
    return make_int4(v.x, v.y, v.z, v.w);
}

// accumulate 8 halfs (16B row quarter) into __shared__ int Q.19 accumulator
// via native ds_add_u32.
__device__ __forceinline__ void accum8_fx(int* a, float4 v){
    const __half2* p = (const __half2*)&v;
#pragma unroll
    for (int k = 0; k < 4; k++){
        float2 f = __half22float2(p[k]);
        atomicAdd(a + 2*k,     __float2int_rn(f.x * FXS));
        atomicAdd(a + 2*k + 1, __float2int_rn(f.y * FXS));
    }
}

// ===== fused: edge binning (chunk-local sort, bin blocks FIRST) | MLP+BN ====
union SMem {
    struct {
        float sW1[3*HF]; float sB1[HF]; float sW2[HF*HF]; float sB2[HF];
        float sh[256][33];
    } mlp;
    struct { int lcnt[2048]; int lbase[2048]; int wsum[4]; } bin;
};

__global__ __launch_bounds__(256)
void k_mlp_bin(const float* __restrict__ x,
               const float* __restrict__ w1, const float* __restrict__ b1,
               const float* __restrict__ w2, const float* __restrict__ b2,
               __half* __restrict__ h, float* __restrict__ stats,
               const int* __restrict__ src, const int* __restrict__ dst,
               int* __restrict__ offs, int* __restrict__ ep,
               int N, int E, int B, int NC){
    __shared__ SMem sm;
    int t = threadIdx.x;
    if ((int)blockIdx.x < NC){
        // ------- binning: count pass captures rank; local prefix; coalesced -
        int bid = blockIdx.x;
        for (int i = t; i < 2048; i += 256) sm.bin.lcnt[i] = 0;
        __syncthreads();
        int base = bid * CH;
        bool full = (base + CH <= E);
        int cntblk = full ? CH : (E - base);
        int rk[64];
        if (full){
#pragma unroll
            for (int i = 0; i < 16; i++){
                int4 d4 = nt_load_i4(dst + base + (t + i*256)*4);
                rk[4*i]   = atomicAdd(&sm.bin.lcnt[d4.x >> BSH], 1);
                rk[4*i+1] = atomicAdd(&sm.bin.lcnt[d4.y >> BSH], 1);
                rk[4*i+2] = atomicAdd(&sm.bin.lcnt[d4.z >> BSH], 1);
                rk[4*i+3] = atomicAdd(&sm.bin.lcnt[d4.w >> BSH], 1);
            }
        } else {
#pragma unroll
            for (int i = 0; i < 64; i++){
                int e = base + t + i*256;
                if (e < E) rk[i] = atomicAdd(&sm.bin.lcnt[dst[e] >> BSH], 1);
            }
        }
        __syncthreads();
        // exclusive prefix over lcnt[0..2047] -> lbase (LOCAL to this chunk)
        {
            int vals[8], ssum = 0;
            int t8 = t*8;
#pragma unroll
            for (int k = 0; k < 8; k++){ vals[k] = sm.bin.lcnt[t8+k]; ssum += vals[k]; }
            int lane = t & 63, wv = t >> 6;
            int v = ssum;
#pragma unroll
            for (int off = 1; off < 64; off <<= 1){
                int u2 = __shfl_up(v, off);
                if (lane >= off) v += u2;
            }
            if (lane == 63) sm.bin.wsum[wv] = v;
            __syncthreads();
            int woff = 0;
            for (int j2 = 0; j2 < wv; j2++) woff += sm.bin.wsum[j2];
            int run = woff + v - ssum;
#pragma unroll
            for (int k = 0; k < 8; k++){ sm.bin.lbase[t8+k] = run; run += vals[k]; }
        }
        __syncthreads();
        // write offset row (coalesced) + scatter within own chunk (L2-local)
        int* orow = offs + (size_t)bid*(B+1);
        for (int i = t; i < B; i += 256) orow[i] = sm.bin.lbase[i];
        if (t == 0) orow[B] = cntblk;
        if (full){
#pragma unroll
            for (int i = 0; i < 16; i++){
                int idx = base + (t + i*256)*4;
                int4 d4 = *(const int4*)(dst + idx);
                int4 s4 = *(const int4*)(src + idx);
                int dd[4] = {d4.x, d4.y, d4.z, d4.w};
                int ss[4] = {s4.x, s4.y, s4.z, s4.w};
#pragma unroll
                for (int k = 0; k < 4; k++){
                    int bb = dd[k] >> BSH;
                    ep[base + sm.bin.lbase[bb] + rk[4*i+k]] = (ss[k] << BSH) | (dd[k] & (BSZ-1));
                }
            }
        } else {
#pragma unroll
            for (int i = 0; i < 64; i++){
                int e = base + t + i*256;
                if (e < E){
                    int d = dst[e], s = src[e];
                    int bb = d >> BSH;
                    ep[base + sm.bin.lbase[bb] + rk[i]] = (s << BSH) | (d & (BSZ-1));
                }
            }
        }
    } else {
        // ---------------- MLP + BN stats ----------------
        for (int i = t; i < 3*HF; i += 256) sm.mlp.sW1[i] = w1[i];
        if (t < HF){ sm.mlp.sB1[t] = b1[t]; sm.mlp.sB2[t] = b2[t]; }
        for (int i = t; i < HF*HF; i += 256) sm.mlp.sW2[i] = w2[i];
        __syncthreads();
        int n = (blockIdx.x - NC)*256 + t;
        float h2[HF];
        if (n < N){
            float x0 = x[(size_t)n*3], x1 = x[(size_t)n*3+1], x2 = x[(size_t)n*3+2];
            float h1[HF];
#pragma unroll
            for (int j = 0; j < HF; j++){
                float v = fmaf(x0, sm.mlp.sW1[j], fmaf(x1, sm.mlp.sW1[HF+j],
                          fmaf(x2, sm.mlp.sW1[2*HF+j], sm.mlp.sB1[j])));
                h1[j] = leaky(v);
            }
#pragma unroll
            for (int j = 0; j < HF; j++){
                float v = sm.mlp.sB2[j];
#pragma unroll
                for (int i = 0; i < HF; i++) v = fmaf(h1[i], sm.mlp.sW2[i*HF+j], v);
                h2[j] = leaky(v);
            }
            float4* hv = (float4*)(h + (size_t)n*HF);
#pragma unroll
            for (int jb = 0; jb < 4; jb++){
                __half2 hh[4];
#pragma unroll
                for (int k = 0; k < 4; k++)
                    hh[k] = __float22half2_rn(make_float2(h2[jb*8+2*k], h2[jb*8+2*k+1]));
                hv[jb] = *(float4*)hh;
            }
        } else {
#pragma unroll
            for (int j = 0; j < HF; j++) h2[j] = 0.f;
        }
#pragma unroll
        for (int j = 0; j < HF; j++) sm.mlp.sh[t][j] = h2[j];
        __syncthreads();
        int f = t & 31, g = t >> 5;
        float s = 0.f, ss = 0.f;
        for (int i = 0; i < 32; i++){
            float v = sm.mlp.sh[g*32 + i][f];
            s += v; ss += v*v;
        }
        __syncthreads();
        sm.mlp.sh[g][f] = s; sm.mlp.sh[8+g][f] = ss;
        __syncthreads();
        if (t < HF){
            float a = 0.f, b = 0.f;
#pragma unroll
            for (int g2 = 0; g2 < 8; g2++){ a += sm.mlp.sh[g2][t]; b += sm.mlp.sh[8+g2][t]; }
            atomicAdd(&stats[t], a);
            atomicAdd(&stats[HF+t], b);
        }
    }
}

// ===== per-bucket: run-gather (thread-per-chunk) + deg + SRC sort + BN+t1 ===
// Bucket b's edges live as NC~153 runs: chunk c at [offs[c][b], offs[c][b+1]).
// Thread t<NC stages run t into LDS; then degree count + 64-bin src sort
// (ep2) + BN + t1 exactly as r14.
__global__ __launch_bounds__(256)
void k_deg_t1(const int* __restrict__ ep, int* __restrict__ ep2,
              const int* __restrict__ offs,
              int* __restrict__ bcnt, float* __restrict__ dis,
              const __half* __restrict__ h, const float* __restrict__ stats,
              const float* __restrict__ gamma, const float* __restrict__ beta,
              const float* __restrict__ W, __half* __restrict__ tout,
              int N, int B, int NC){
    __shared__ union { int sep[CAP]; float hsh[BSZ][HF+1]; } u;
    __shared__ int lcnt[BSZ];
    __shared__ int sbc[64], sbo[64], sbf[64];
    __shared__ int wsum4[4];
    __shared__ float sW[HF*HF];
    __shared__ float sscale[HF], sshift[HF];
    int t = threadIdx.x;
    int b = blockIdx.x;
    for (int i = t; i < HF*HF; i += 256) sW[i] = W[i];
    if (t < HF){
        float inv = 1.0f/(float)N;
        float mu  = stats[t]*inv;
        float var = stats[HF+t]*inv - mu*mu;
        float rs  = rsqrtf(var + EPS);
        float sc  = rs*gamma[t];
        sscale[t] = sc;
        sshift[t] = beta[t] - mu*sc;
    }
    if (t < BSZ) lcnt[t] = 0;
    if (t < 64){ sbc[t] = 0; sbf[t] = 0; }
    // run info for this thread's chunk (NC <= 256 by construction)
    int myst = 0, mylen = 0;
    if (t < NC){
        const int* op = offs + (size_t)t*(B+1) + b;
        myst  = op[0];
        mylen = op[1] - op[0];
    }
    // 256-thread exclusive scan of run lengths -> LDS dest offsets + total
    int lane = t & 63, wv = t >> 6;
    int v = mylen;
#pragma unroll
    for (int off = 1; off < 64; off <<= 1){
        int u2 = __shfl_up(v, off);
        if (lane >= off) v += u2;
    }
    if (lane == 63) wsum4[wv] = v;
    __syncthreads();
    int woff = 0;
    for (int j2 = 0; j2 < wv; j2++) woff += wsum4[j2];
    int dst0 = woff + v - mylen;
    int cnt = wsum4[0] + wsum4[1] + wsum4[2] + wsum4[3];
    if (t == 0) bcnt[b] = cnt;
    // stage runs + count degrees + src-bin histogram (v>>17 == src>>11, <64)
    if (t < NC && mylen > 0){
        const int* sp = ep + (size_t)t*CH + myst;
        for (int k = 0; k < mylen; k++){
            int vv = sp[k];
            u.sep[dst0 + k] = vv;
            atomicAdd(&lcnt[vv & (BSZ-1)], 1);
            atomicAdd(&sbc[vv >> 17], 1);
        }
    }
    __syncthreads();
    // 64-bin exclusive prefix via wave-0 shuffle scan
    if (t < 64){
        int val = sbc[t];
#pragma unroll
        for (int off = 1; off < 64; off <<= 1){
            int v2 = __shfl_up(val, off);
            if (t >= off) val += v2;
        }
        sbo[t] = val - sbc[t];
    }
    __syncthreads();
    // scatter src-sorted into ep2
    for (int e = t; e < cnt; e += 256){
        int vv = u.sep[e];
        int bin = vv >> 17;
        int p = sbo[bin] + atomicAdd(&sbf[bin], 1);
        ep2[(size_t)b*CAP + p] = vv;
    }
    __syncthreads();   // sep dead; union flips to hsh
    // ------- BN + t1: 4 threads per node, 8 features each -------------------
    int nloc = t >> 2, q = t & 3;
    int n = b*BSZ + nloc;
    float dloc = 0.f;
    if (n < N){
        dloc = rsqrtf((float)lcnt[nloc] + 1.0f);
        if (q == 0) dis[n] = dloc;
        float4 raw = ((const float4*)h)[(size_t)n*4 + q];
        const __half2* p2 = (const __half2*)&raw;
#pragma unroll
        for (int k = 0; k < 4; k++){
            float2 f2 = __half22float2(p2[k]);
            int f = 8*q + 2*k;
            u.hsh[nloc][f]   = fmaf(f2.x, sscale[f],   sshift[f]);
            u.hsh[nloc][f+1] = fmaf(f2.y, sscale[f+1], sshift[f+1]);
        }
    }
    __syncthreads();
    if (n < N){
        int fo = 8*q;
        float o[8] = {0.f,0.f,0.f,0.f,0.f,0.f,0.f,0.f};
#pragma unroll
        for (int i = 0; i < HF; i++){
            float vi = u.hsh[nloc][i];
            float4 w0 = *(const float4*)&sW[i*HF + fo];
            float4 w1 = *(const float4*)&sW[i*HF + fo + 4];
            o[0] = fmaf(vi, w0.x, o[0]); o[1] = fmaf(vi, w0.y, o[1]);
            o[2] = fmaf(vi, w0.z, o[2]); o[3] = fmaf(vi, w0.w, o[3]);
            o[4] = fmaf(vi, w1.x, o[4]); o[5] = fmaf(vi, w1.y, o[5]);
            o[6] = fmaf(vi, w1.z, o[6]); o[7] = fmaf(vi, w1.w, o[7]);
        }
        __half2 hh[4];
#pragma unroll
        for (int k = 0; k < 4; k++)
            hh[k] = __float22half2_rn(make_float2(o[2*k]*dloc, o[2*k+1]*dloc));
        ((float4*)tout)[(size_t)n*4 + q] = *(float4*)hh;
    }
}

// ===== edge-parallel gather per bucket (ds_add_u32 Q.19, 4-deep MLP) ========
__global__ __launch_bounds__(256)
void k_gather_t(const __half* __restrict__ tin, const int* __restrict__ ep,
                const int* __restrict__ bcnt, const float* __restrict__ dis,
                const float* __restrict__ bias, const float* __restrict__ W,
                __half* __restrict__ tout, int N){
    __shared__ int iacc[BSZ][HF+1];
    __shared__ float sW[HF*HF];
    float* facc = (float*)iacc;             // reused as float after finish
    int t = threadIdx.x, b = blockIdx.x;
    for (int i = t; i < HF*HF; i += 256) sW[i] = W[i];
    for (int i = t; i < BSZ*(HF+1); i += 256) ((int*)iacc)[i] = 0;
    int cnt = bcnt[b];
    size_t base = (size_t)b*CAP;
    __syncthreads();
    int g = t >> 2, l = t & 3;
    const float4* tv = (const float4*)tin;
    int j = g;
    for (; j + 192 < cnt; j += 256){        // 4 rows in flight per group
        int p0 = ep[base + j];
        int p1 = ep[base + j + 64];
        int p2 = ep[base + j + 128];
        int p3 = ep[base + j + 192];
        float4 r0 = tv[(size_t)(p0 >> BSH)*4 + l];
        float4 r1 = tv[(size_t)(p1 >> BSH)*4 + l];
        float4 r2 = tv[(size_t)(p2 >> BSH)*4 + l];
        float4 r3 = tv[(size_t)(p3 >> BSH)*4 + l];
        accum8_fx(&iacc[p0 & (BSZ-1)][8*l], r0);
        accum8_fx(&iacc[p1 & (BSZ-1)][8*l], r1);
        accum8_fx(&iacc[p2 & (BSZ-1)][8*l], r2);
        accum8_fx(&iacc[p3 & (BSZ-1)][8*l], r3);
    }
    for (; j + 64 < cnt; j += 128){
        int p0 = ep[base + j], p1 = ep[base + j + 64];
        float4 r0 = tv[(size_t)(p0 >> BSH)*4 + l];
        float4 r1 = tv[(size_t)(p1 >> BSH)*4 + l];
        accum8_fx(&iacc[p0 & (BSZ-1)][8*l], r0);
        accum8_fx(&iacc[p1 & (BSZ-1)][8*l], r1);
    }
    for (; j < cnt; j += 64){
        int p0 = ep[base + j];
        float4 r0 = tv[(size_t)(p0 >> BSH)*4 + l];
        accum8_fx(&iacc[p0 & (BSZ-1)][8*l], r0);
    }
    __syncthreads();
    // ------- finish: 4 threads/node: fx->f32, +self, *dis, +bias, elu -------
    int nloc = t >> 2, q = t & 3;
    int n = b*BSZ + nloc;
    float dv = 0.f;
    float fin[8];
    if (n < N){
        dv = dis[n];
        float4 s0 = tv[(size_t)n*4 + q];
        const __half2* ph = (const __half2*)&s0;
#pragma unroll
        for (int k = 0; k < 4; k++){
            float2 f2 = __half22float2(ph[k]);
            int f = 8*q + 2*k;
            float a0 = (float)iacc[nloc][f]   * FXI + f2.x;
            float a1 = (float)iacc[nloc][f+1] * FXI + f2.y;
            fin[2*k]   = elu1(fmaf(dv, a0, bias[f]));
            fin[2*k+1] = elu1(fmaf(dv, a1, bias[f+1]));
        }
    }
    __syncthreads();
    if (n < N){
#pragma unroll
        for (int k = 0; k < 8; k++) facc[nloc*(HF+1) + 8*q + k] = fin[k];
    }
    __syncthreads();
    // ------- transform: o = (hnext @ W) * dis, fp16 store -------------------
    if (n < N){
        int fo = 8*q;
        float o[8] = {0.f,0.f,0.f,0.f,0.f,0.f,0.f,0.f};
#pragma unroll
        for (int i = 0; i < HF; i++){
            float hv = facc[nloc*(HF+1) + i];
            float4 w0 = *(const float4*)&sW[i*HF + fo];
            float4 w1 = *(const float4*)&sW[i*HF + fo + 4];
            o[0] = fmaf(hv, w0.x, o[0]); o[1] = fmaf(hv, w0.y, o[1]);
            o[2] = fmaf(hv, w0.z, o[2]); o[3] = fmaf(hv, w0.w, o[3]);
            o[4] = fmaf(hv, w1.x, o[4]); o[5] = fmaf(hv, w1.y, o[5]);
            o[6] = fmaf(hv, w1.z, o[6]); o[7] = fmaf(hv, w1.w, o[7]);
        }
        __half2 hh[4];
#pragma unroll
        for (int k = 0; k < 4; k++)
            hh[k] = __float22half2_rn(make_float2(o[2*k]*dv, o[2*k+1]*dv));
        ((float4*)tout)[(size_t)n*4 + q] = *(float4*)hh;
    }
}

// ===== edge-parallel gather + elu + output MLP + sigmoid col 0 ==============
__global__ __launch_bounds__(256)
void k_gather_out(const __half* __restrict__ tin, const int* __restrict__ ep,
                  const int* __restrict__ bcnt, const float* __restrict__ dis,
                  const float* __restrict__ bg3,
                  const float* __restrict__ wo1, const float* __restrict__ bo1,
                  const float* __restrict__ wo2, const float* __restrict__ bo2,
                  const float* __restrict__ wo3, const float* __restrict__ bo3,
                  float* __restrict__ out, int N){
    __shared__ int iacc[BSZ][HF+1];
    __shared__ float sW1[HF*HF], sW2[HF*HF], sW3[HF*4];
    float* facc = (float*)iacc;
    int t = threadIdx.x, b = blockIdx.x;
    for (int i = t; i < HF*HF; i += 256){ sW1[i] = wo1[i]; sW2[i] = wo2[i]; }
    if (t < HF*4) sW3[t] = wo3[t];
    for (int i = t; i < BSZ*(HF+1); i += 256) ((int*)iacc)[i] = 0;
    int cnt = bcnt[b];
    size_t base = (size_t)b*CAP;
    __syncthreads();
    int g = t >> 2, l = t & 3;
    const float4* tv = (const float4*)tin;
    int j = g;
    for (; j + 192 < cnt; j += 256){        // 4 rows in flight per group
        int p0 = ep[base + j];
        int p1 = ep[base + j + 64];
        int p2 = ep[base + j + 128];
        int p3 = ep[base + j + 192];
        float4 r0 = tv[(size_t)(p0 >> BSH)*4 + l];
        float4 r1 = tv[(size_t)(p1 >> BSH)*4 + l];
        float4 r2 = tv[(size_t)(p2 >> BSH)*4 + l];
        float4 r3 = tv[(size_t)(p3 >> BSH)*4 + l];
        accum8_fx(&iacc[p0 & (BSZ-1)][8*l], r0);
        accum8_fx(&iacc[p1 & (BSZ-1)][8*l], r1);
        accum8_fx(&iacc[p2 & (BSZ-1)][8*l], r2);
        accum8_fx(&iacc[p3 & (BSZ-1)][8*l], r3);
    }
    for (; j + 64 < cnt; j += 128){
        int p0 = ep[base + j], p1 = ep[base + j + 64];
        float4 r0 = tv[(size_t)(p0 >> BSH)*4 + l];
        float4 r1 = tv[(size_t)(p1 >> BSH)*4 + l];
        accum8_fx(&iacc[p0 & (BSZ-1)][8*l], r0);
        accum8_fx(&iacc[p1 & (BSZ-1)][8*l], r1);
    }
    for (; j < cnt; j += 64){
        int p0 = ep[base + j];
        float4 r0 = tv[(size_t)(p0 >> BSH)*4 + l];
        accum8_fx(&iacc[p0 & (BSZ-1)][8*l], r0);
    }
    __syncthreads();
    int nloc = t >> 2, q = t & 3;
    int n = b*BSZ + nloc;
    // finish: fx->f32 + self + dis + bg3 + elu -> facc (h for output MLP)
    float fin[8];
    if (n < N){
        float dv = dis[n];
        float4 s0 = tv[(size_t)n*4 + q];
        const __half2* ph = (const __half2*)&s0;
#pragma unroll
        for (int k = 0; k < 4; k++){
            float2 f2 = __half22float2(ph[k]);
            int f = 8*q + 2*k;
            float a0 = (float)iacc[nloc][f]   * FXI + f2.x;
            float a1 = (float)iacc[nloc][f+1] * FXI + f2.y;
            fin[2*k]   = elu1(fmaf(dv, a0, bg3[f]));
            fin[2*k+1] = elu1(fmaf(dv, a1, bg3[f+1]));
        }
    }
    __syncthreads();
    if (n < N){
#pragma unroll
        for (int k = 0; k < 8; k++) facc[nloc*(HF+1) + 8*q + k] = fin[k];
    }
    __syncthreads();
    // o1 = leaky(h @ Wo1 + bo1)
    float o1[8];
    if (n < N){
        int fo = 8*q;
#pragma unroll
        for (int c = 0; c < 8; c++) o1[c] = bo1[fo + c];
#pragma unroll
        for (int i = 0; i < HF; i++){
            float hv = facc[nloc*(HF+1) + i];
            float4 w0 = *(const float4*)&sW1[i*HF + fo];
            float4 w1 = *(const float4*)&sW1[i*HF + fo + 4];
            o1[0] = fmaf(hv, w0.x, o1[0]); o1[1] = fmaf(hv, w0.y, o1[1]);
            o1[2] = fmaf(hv, w0.z, o1[2]); o1[3] = fmaf(hv, w0.w, o1[3]);
            o1[4] = fmaf(hv, w1.x, o1[4]); o1[5] = fmaf(hv, w1.y, o1[5]);
            o1[6] = fmaf(hv, w1.z, o1[6]); o1[7] = fmaf(hv, w1.w, o1[7]);
        }
    }
    __syncthreads();
    if (n < N){
        int fo = 8*q;
#pragma unroll
        for (int c = 0; c < 8; c++) facc[nloc*(HF+1) + fo + c] = leaky(o1[c]);
    }
    __syncthreads();
    // o2 = leaky(o1 @ Wo2 + bo2)
    float o2[8];
    if (n < N){
        int fo = 8*q;
#pragma unroll
        for (int c = 0; c < 8; c++) o2[c] = bo2[fo + c];
#pragma unroll
        for (int i = 0; i < HF; i++){
            float hv = facc[nloc*(HF+1) + i];
            float4 w0 = *(const float4*)&sW2[i*HF + fo];
            float4 w1 = *(const float4*)&sW2[i*HF + fo + 4];
            o2[0] = fmaf(hv, w0.x, o2[0]); o2[1] = fmaf(hv, w0.y, o2[1]);
            o2[2] = fmaf(hv, w0.z, o2[2]); o2[3] = fmaf(hv, w0.w, o2[3]);
            o2[4] = fmaf(hv, w1.x, o2[4]); o2[5] = fmaf(hv, w1.y, o2[5]);
            o2[6] = fmaf(hv, w1.z, o2[6]); o2[7] = fmaf(hv, w1.w, o2[7]);
        }
    }
    __syncthreads();
    if (n < N){
        int fo = 8*q;
#pragma unroll
        for (int c = 0; c < 8; c++) facc[nloc*(HF+1) + fo + c] = leaky(o2[c]);
    }
    __syncthreads();
    // final: 4 threads/node, 1 output each
    if (n < N){
        float v = bo3[q];
#pragma unroll
        for (int i = 0; i < HF; i++) v = fmaf(facc[nloc*(HF+1) + i], sW3[i*4 + q], v);
        if (q == 0) v = sigmoidf(v);
        out[(size_t)n*4 + q] = v;
    }
}

extern "C" void kernel_launch(void* const* d_in, const int* in_sizes, int n_in,
                              void* d_out, int out_size, void* d_ws, size_t ws_size,
                              hipStream_t stream) {
    const float* x     = (const float*)d_in[0];
    const float* w_in1 = (const float*)d_in[1];
    const float* b_in1 = (const float*)d_in[2];
    const float* w_in2 = (const float*)d_in[3];
    const float* b_in2 = (const float*)d_in[4];
    const float* gamma = (const float*)d_in[5];
    const float* beta  = (const float*)d_in[6];
    const float* wg1   = (const float*)d_in[7];
    const float* bg1   = (const float*)d_in[8];
    const float* wg2   = (const float*)d_in[9];
    const float* bg2   = (const float*)d_in[10];
    const float* wg3   = (const float*)d_in[11];
    const float* bg3   = (const float*)d_in[12];
    const float* wo1   = (const float*)d_in[13];
    const float* bo1   = (const float*)d_in[14];
    const float* wo2   = (const float*)d_in[15];
    const float* bo2   = (const float*)d_in[16];
    const float* wo3   = (const float*)d_in[17];
    const float* bo3   = (const float*)d_in[18];
    const int*   ei    = (const int*)d_in[19];

    int N = in_sizes[0] / 3;
    int E = in_sizes[19] / 2;
    int B = (N + BSZ - 1) >> BSH;          // buckets (1563; lcnt arrays hold 2048)
    int NC = (E + CH - 1) / CH;            // 153 chunks (must stay <= 256)

    char* w = (char*)d_ws;
    size_t o = 0;
    auto alloc = [&](size_t bytes){ size_t r = o; o = (o + bytes + 255) & ~(size_t)255; return r; };
    // ---- zeroed region ----
    float* stats = (float*)(w + alloc(2*HF*sizeof(float)));
    size_t zero_bytes = o;
    // ---- rest ----
    int*   offs  = (int*)  (w + alloc((size_t)NC*(B+1)*4));
    int*   bcnt  = (int*)  (w + alloc((size_t)B*4));
    float* dis   = (float*)(w + alloc((size_t)N*4));
    int*   ep    = (int*)  (w + alloc((size_t)NC*CH*4));
    int*   ep2   = (int*)  (w + alloc((size_t)B*CAP*4));
    __half* bufH = (__half*)(w + alloc((size_t)N*HF*2));
    __half* tA   = (__half*)(w + alloc((size_t)N*HF*2));
    __half* tB   = (__half*)(w + alloc((size_t)N*HF*2));

    hipMemsetAsync(d_ws, 0, zero_bytes, stream);

    const int* src = ei;
    const int* dst = ei + E;
    int NB1 = (N + 255) / 256;

    k_mlp_bin<<<NC + NB1, 256, 0, stream>>>(x, w_in1, b_in1, w_in2, b_in2, bufH, stats,
                                            src, dst, offs, ep, N, E, B, NC);
    k_deg_t1<<<B, 256, 0, stream>>>(ep, ep2, offs, bcnt, dis,
                                    bufH, stats, gamma, beta, wg1, tA, N, B, NC);
    k_gather_t<<<B, 256, 0, stream>>>(tA, ep2, bcnt, dis, bg1, wg2, tB, N);
    k_gather_t<<<B, 256, 0, stream>>>(tB, ep2, bcnt, dis, bg2, wg3, tA, N);
    k_gather_out<<<B, 256, 0, stream>>>(tA, ep2, bcnt, dis, bg3,
                                        wo1, bo1, wo2, bo2, wo3, bo3, (float*)d_out, N);
}

// Round 18
// 256.255 us; speedup vs baseline: 1.0265x; 1.0265x over previous
//
#include <hip/hip_runtime.h>
#include <hip/hip_fp16.h>

#define HF 32
#define EPS 1e-5f
#define BSH 6
#define BSZ 64           // nodes per bucket
#define CH  16384        // edges per binning block (two-pass, L2-hot re-read)
#define SUBCAP 320       // per-XCD sub-segment capacity (mean 200 + 8.5 sigma)
#define CAP (8*SUBCAP)   // bucket segment capacity (2560)
#define FXS 524288.0f    // 2^19 fixed-point scale (range +-4096, quant 1.9e-6)
#define FXI (1.0f/524288.0f)

typedef int vi4 __attribute__((ext_vector_type(4)));

__device__ __forceinline__ float leaky(float v){ return fmaxf(v, 0.01f*v); }
__device__ __forceinline__ float elu1(float v){ return v > 0.f ? v : (expf(v)-1.f); }
__device__ __forceinline__ float sigmoidf(float v){ return 1.f/(1.f+expf(-v)); }

// LESSONS: nt stores on scattered writes -> 143MB writeback. Scattered
// global atomics -> +84MB (r1). Degree-sorted NODE order -> imbalance (r2).
// FP atomics into LDS (any spelling) -> flat/CAS, 10-30x (r4/r6).
// Persistent kernel + grid barriers -> L2 flush (r7). INT LDS atomics
// fast -> Q.19 accumulation (r9). Gathers TLP/DS/MLP-insensitive
// (r10/r11/r12). Rank-capture binning -6us (r13). SRC counting-sort ->
// -10us (BEST: 258.8us). Unified bin+MLP (r15), nt ep loads (r16),
// chunk-local sorted binning (r17) ALL regressed -> binning is at a
// fixed scatter-transaction floor; gathers at random-row service rate.
// THIS ROUND: exact revert to the best-measured configuration.
__device__ __forceinline__ int4 nt_load_i4(const int* p){
    vi4 v = __builtin_nontemporal_load((const vi4*)p);
    return make_int4(v.x, v.y, v.z, v.w);
}

// accumulate 8 halfs (16B row quarter) into __shared__ int Q.19 accumulator
// via native ds_add_u32.
__device__ __forceinline__ void accum8_fx(int* a, float4 v){
    const __half2* p = (const __half2*)&v;
#pragma unroll
    for (int k = 0; k < 4; k++){
        float2 f = __half22float2(p[k]);
        atomicAdd(a + 2*k,     __float2int_rn(f.x * FXS));
        atomicAdd(a + 2*k + 1, __float2int_rn(f.y * FXS));
    }
}

// ===== fused: edge binning (rank-capture, bin blocks FIRST) | MLP + BN ======
union SMem {
    struct {
        float sW1[3*HF]; float sB1[HF]; float sW2[HF*HF]; float sB2[HF];
        float sh[256][33];
    } mlp;
    struct { int lcnt[2048]; int lbase[2048]; } bin;
};

__global__ __launch_bounds__(256)
void k_mlp_bin(const float* __restrict__ x,
               const float* __restrict__ w1, const float* __restrict__ b1,
               const float* __restrict__ w2, const float* __restrict__ b2,
               __half* __restrict__ h, float* __restrict__ stats,
               const int* __restrict__ src, const int* __restrict__ dst,
               int* __restrict__ gfill, int* __restrict__ ep,
               int N, int E, int B, int NC){
    __shared__ SMem sm;
    int t = threadIdx.x;
    if ((int)blockIdx.x < NC){
        // ------- binning: count pass captures rank; scatter has NO atomics --
        int bid = blockIdx.x;
        for (int i = t; i < B; i += 256) sm.bin.lcnt[i] = 0;
        __syncthreads();
        int base = bid * CH;
        int xcd = bid & 7;
        bool full = (base + CH <= E);
        int rk[64];
        if (full){
#pragma unroll
            for (int i = 0; i < 16; i++){
                int4 d4 = nt_load_i4(dst + base + (t + i*256)*4);
                rk[4*i]   = atomicAdd(&sm.bin.lcnt[d4.x >> BSH], 1);
                rk[4*i+1] = atomicAdd(&sm.bin.lcnt[d4.y >> BSH], 1);
                rk[4*i+2] = atomicAdd(&sm.bin.lcnt[d4.z >> BSH], 1);
                rk[4*i+3] = atomicAdd(&sm.bin.lcnt[d4.w >> BSH], 1);
            }
        } else {
#pragma unroll
            for (int i = 0; i < 64; i++){
                int e = base + t + i*256;
                if (e < E) rk[i] = atomicAdd(&sm.bin.lcnt[dst[e] >> BSH], 1);
            }
        }
        __syncthreads();
        // reserve contiguous range in this block's xcd sub-segment per bucket
        for (int i = t; i < B; i += 256){
            int c = sm.bin.lcnt[i];
            sm.bin.lbase[i] = c ? (i*CAP + xcd*SUBCAP + atomicAdd(&gfill[i*8 + xcd], c)) : 0;
        }
        __syncthreads();
        // scatter: re-read edges (L2-hot), position = lbase + captured rank
        if (full){
#pragma unroll
            for (int i = 0; i < 16; i++){
                int idx = base + (t + i*256)*4;
                int4 d4 = *(const int4*)(dst + idx);
                int4 s4 = *(const int4*)(src + idx);
                int dd[4] = {d4.x, d4.y, d4.z, d4.w};
                int ss[4] = {s4.x, s4.y, s4.z, s4.w};
#pragma unroll
                for (int k = 0; k < 4; k++){
                    int bb = dd[k] >> BSH;
                    ep[sm.bin.lbase[bb] + rk[4*i+k]] = (ss[k] << BSH) | (dd[k] & (BSZ-1));
                }
            }
        } else {
#pragma unroll
            for (int i = 0; i < 64; i++){
                int e = base + t + i*256;
                if (e < E){
                    int d = dst[e], s = src[e];
                    int bb = d >> BSH;
                    ep[sm.bin.lbase[bb] + rk[i]] = (s << BSH) | (d & (BSZ-1));
                }
            }
        }
    } else {
        // ---------------- MLP + BN stats ----------------
        for (int i = t; i < 3*HF; i += 256) sm.mlp.sW1[i] = w1[i];
        if (t < HF){ sm.mlp.sB1[t] = b1[t]; sm.mlp.sB2[t] = b2[t]; }
        for (int i = t; i < HF*HF; i += 256) sm.mlp.sW2[i] = w2[i];
        __syncthreads();
        int n = (blockIdx.x - NC)*256 + t;
        float h2[HF];
        if (n < N){
            float x0 = x[(size_t)n*3], x1 = x[(size_t)n*3+1], x2 = x[(size_t)n*3+2];
            float h1[HF];
#pragma unroll
            for (int j = 0; j < HF; j++){
                float v = fmaf(x0, sm.mlp.sW1[j], fmaf(x1, sm.mlp.sW1[HF+j],
                          fmaf(x2, sm.mlp.sW1[2*HF+j], sm.mlp.sB1[j])));
                h1[j] = leaky(v);
            }
#pragma unroll
            for (int j = 0; j < HF; j++){
                float v = sm.mlp.sB2[j];
#pragma unroll
                for (int i = 0; i < HF; i++) v = fmaf(h1[i], sm.mlp.sW2[i*HF+j], v);
                h2[j] = leaky(v);
            }
            float4* hv = (float4*)(h + (size_t)n*HF);
#pragma unroll
            for (int jb = 0; jb < 4; jb++){
                __half2 hh[4];
#pragma unroll
                for (int k = 0; k < 4; k++)
                    hh[k] = __float22half2_rn(make_float2(h2[jb*8+2*k], h2[jb*8+2*k+1]));
                hv[jb] = *(float4*)hh;
            }
        } else {
#pragma unroll
            for (int j = 0; j < HF; j++) h2[j] = 0.f;
        }
#pragma unroll
        for (int j = 0; j < HF; j++) sm.mlp.sh[t][j] = h2[j];
        __syncthreads();
        int f = t & 31, g = t >> 5;
        float s = 0.f, ss = 0.f;
        for (int i = 0; i < 32; i++){
            float v = sm.mlp.sh[g*32 + i][f];
            s += v; ss += v*v;
        }
        __syncthreads();
        sm.mlp.sh[g][f] = s; sm.mlp.sh[8+g][f] = ss;
        __syncthreads();
        if (t < HF){
            float a = 0.f, b = 0.f;
#pragma unroll
            for (int g2 = 0; g2 < 8; g2++){ a += sm.mlp.sh[g2][t]; b += sm.mlp.sh[8+g2][t]; }
            atomicAdd(&stats[t], a);
            atomicAdd(&stats[HF+t], b);
        }
    }
}

// ===== per-bucket: deg count + SRC-ORDER counting sort (ep->ep2) + BN+t1 ====
// 64 src-bins (src>>11, 128KB of tin each). Gathers then sweep tin in
// ascending-src order -> the ~25x per-row reuse lands in L2 instead of HBM.
__global__ __launch_bounds__(256)
void k_deg_t1(const int* __restrict__ ep, int* __restrict__ ep2,
              const int* __restrict__ gfill,
              int* __restrict__ bcnt, float* __restrict__ dis,
              const __half* __restrict__ h, const float* __restrict__ stats,
              const float* __restrict__ gamma, const float* __restrict__ beta,
              const float* __restrict__ W, __half* __restrict__ tout,
              int N, int B){
    __shared__ union { int sep[CAP]; float hsh[BSZ][HF+1]; } u;
    __shared__ int lcnt[BSZ];
    __shared__ int sbc[64], sbo[64], sbf[64];
    __shared__ float sW[HF*HF];
    __shared__ float sscale[HF], sshift[HF];
    int t = threadIdx.x;
    int b = blockIdx.x;
    for (int i = t; i < HF*HF; i += 256) sW[i] = W[i];
    if (t < HF){
        float inv = 1.0f/(float)N;
        float mu  = stats[t]*inv;
        float var = stats[HF+t]*inv - mu*mu;
        float rs  = rsqrtf(var + EPS);
        float sc  = rs*gamma[t];
        sscale[t] = sc;
        sshift[t] = beta[t] - mu*sc;
    }
    if (t < BSZ) lcnt[t] = 0;
    if (t < 64){ sbc[t] = 0; sbf[t] = 0; }
    int cx[8], coff[8], cnt = 0;
#pragma unroll
    for (int xx = 0; xx < 8; xx++){ cx[xx] = gfill[b*8 + xx]; coff[xx] = cnt; cnt += cx[xx]; }
    int base = b*CAP;
    __syncthreads();
    // stage + count: dst degree + src-bin histogram (v>>17 == src>>11, <64)
#pragma unroll
    for (int xx = 0; xx < 8; xx++){
        const int* seg = ep + base + xx*SUBCAP;
        for (int j = t; j < cx[xx]; j += 256){
            int v = seg[j];
            u.sep[coff[xx] + j] = v;
            atomicAdd(&lcnt[v & (BSZ-1)], 1);
            atomicAdd(&sbc[v >> 17], 1);
        }
    }
    if (t == 0) bcnt[b] = cnt;
    __syncthreads();
    // 64-bin exclusive prefix via wave-0 shuffle scan
    if (t < 64){
        int val = sbc[t];
#pragma unroll
        for (int off = 1; off < 64; off <<= 1){
            int v2 = __shfl_up(val, off);
            if (t >= off) val += v2;
        }
        sbo[t] = val - sbc[t];
    }
    __syncthreads();
    // scatter src-sorted into ep2
    for (int e = t; e < cnt; e += 256){
        int v = u.sep[e];
        int bin = v >> 17;
        int p = sbo[bin] + atomicAdd(&sbf[bin], 1);
        ep2[base + p] = v;
    }
    __syncthreads();   // sep dead; union flips to hsh
    // ------- BN + t1: 4 threads per node, 8 features each -------------------
    int nloc = t >> 2, q = t & 3;
    int n = b*BSZ + nloc;
    float dloc = 0.f;
    if (n < N){
        dloc = rsqrtf((float)lcnt[nloc] + 1.0f);
        if (q == 0) dis[n] = dloc;
        float4 raw = ((const float4*)h)[(size_t)n*4 + q];
        const __half2* p2 = (const __half2*)&raw;
#pragma unroll
        for (int k = 0; k < 4; k++){
            float2 f2 = __half22float2(p2[k]);
            int f = 8*q + 2*k;
            u.hsh[nloc][f]   = fmaf(f2.x, sscale[f],   sshift[f]);
            u.hsh[nloc][f+1] = fmaf(f2.y, sscale[f+1], sshift[f+1]);
        }
    }
    __syncthreads();
    if (n < N){
        int fo = 8*q;
        float o[8] = {0.f,0.f,0.f,0.f,0.f,0.f,0.f,0.f};
#pragma unroll
        for (int i = 0; i < HF; i++){
            float vi = u.hsh[nloc][i];
            float4 w0 = *(const float4*)&sW[i*HF + fo];
            float4 w1 = *(const float4*)&sW[i*HF + fo + 4];
            o[0] = fmaf(vi, w0.x, o[0]); o[1] = fmaf(vi, w0.y, o[1]);
            o[2] = fmaf(vi, w0.z, o[2]); o[3] = fmaf(vi, w0.w, o[3]);
            o[4] = fmaf(vi, w1.x, o[4]); o[5] = fmaf(vi, w1.y, o[5]);
            o[6] = fmaf(vi, w1.z, o[6]); o[7] = fmaf(vi, w1.w, o[7]);
        }
        __half2 hh[4];
#pragma unroll
        for (int k = 0; k < 4; k++)
            hh[k] = __float22half2_rn(make_float2(o[2*k]*dloc, o[2*k+1]*dloc));
        ((float4*)tout)[(size_t)n*4 + q] = *(float4*)hh;
    }
}

// ===== edge-parallel gather per bucket (ds_add_u32 Q.19, 4-deep MLP) ========
__global__ __launch_bounds__(256)
void k_gather_t(const __half* __restrict__ tin, const int* __restrict__ ep,
                const int* __restrict__ bcnt, const float* __restrict__ dis,
                const float* __restrict__ bias, const float* __restrict__ W,
                __half* __restrict__ tout, int N){
    __shared__ int iacc[BSZ][HF+1];
    __shared__ float sW[HF*HF];
    float* facc = (float*)iacc;             // reused as float after finish
    int t = threadIdx.x, b = blockIdx.x;
    for (int i = t; i < HF*HF; i += 256) sW[i] = W[i];
    for (int i = t; i < BSZ*(HF+1); i += 256) ((int*)iacc)[i] = 0;
    int cnt = bcnt[b];
    int base = b*CAP;
    __syncthreads();
    int g = t >> 2, l = t & 3;
    const float4* tv = (const float4*)tin;
    int j = g;
    for (; j + 192 < cnt; j += 256){        // 4 rows in flight per group
        int p0 = ep[base + j];
        int p1 = ep[base + j + 64];
        int p2 = ep[base + j + 128];
        int p3 = ep[base + j + 192];
        float4 r0 = tv[(size_t)(p0 >> BSH)*4 + l];
        float4 r1 = tv[(size_t)(p1 >> BSH)*4 + l];
        float4 r2 = tv[(size_t)(p2 >> BSH)*4 + l];
        float4 r3 = tv[(size_t)(p3 >> BSH)*4 + l];
        accum8_fx(&iacc[p0 & (BSZ-1)][8*l], r0);
        accum8_fx(&iacc[p1 & (BSZ-1)][8*l], r1);
        accum8_fx(&iacc[p2 & (BSZ-1)][8*l], r2);
        accum8_fx(&iacc[p3 & (BSZ-1)][8*l], r3);
    }
    for (; j + 64 < cnt; j += 128){
        int p0 = ep[base + j], p1 = ep[base + j + 64];
        float4 r0 = tv[(size_t)(p0 >> BSH)*4 + l];
        float4 r1 = tv[(size_t)(p1 >> BSH)*4 + l];
        accum8_fx(&iacc[p0 & (BSZ-1)][8*l], r0);
        accum8_fx(&iacc[p1 & (BSZ-1)][8*l], r1);
    }
    for (; j < cnt; j += 64){
        int p0 = ep[base + j];
        float4 r0 = tv[(size_t)(p0 >> BSH)*4 + l];
        accum8_fx(&iacc[p0 & (BSZ-1)][8*l], r0);
    }
    __syncthreads();
    // ------- finish: 4 threads/node: fx->f32, +self, *dis, +bias, elu -------
    int nloc = t >> 2, q = t & 3;
    int n = b*BSZ + nloc;
    float dv = 0.f;
    float fin[8];
    if (n < N){
        dv = dis[n];
        float4 s0 = tv[(size_t)n*4 + q];
        const __half2* ph = (const __half2*)&s0;
#pragma unroll
        for (int k = 0; k < 4; k++){
            float2 f2 = __half22float2(ph[k]);
            int f = 8*q + 2*k;
            float a0 = (float)iacc[nloc][f]   * FXI + f2.x;
            float a1 = (float)iacc[nloc][f+1] * FXI + f2.y;
            fin[2*k]   = elu1(fmaf(dv, a0, bias[f]));
            fin[2*k+1] = elu1(fmaf(dv, a1, bias[f+1]));
        }
    }
    __syncthreads();
    if (n < N){
#pragma unroll
        for (int k = 0; k < 8; k++) facc[nloc*(HF+1) + 8*q + k] = fin[k];
    }
    __syncthreads();
    // ------- transform: o = (hnext @ W) * dis, fp16 store -------------------
    if (n < N){
        int fo = 8*q;
        float o[8] = {0.f,0.f,0.f,0.f,0.f,0.f,0.f,0.f};
#pragma unroll
        for (int i = 0; i < HF; i++){
            float hv = facc[nloc*(HF+1) + i];
            float4 w0 = *(const float4*)&sW[i*HF + fo];
            float4 w1 = *(const float4*)&sW[i*HF + fo + 4];
            o[0] = fmaf(hv, w0.x, o[0]); o[1] = fmaf(hv, w0.y, o[1]);
            o[2] = fmaf(hv, w0.z, o[2]); o[3] = fmaf(hv, w0.w, o[3]);
            o[4] = fmaf(hv, w1.x, o[4]); o[5] = fmaf(hv, w1.y, o[5]);
            o[6] = fmaf(hv, w1.z, o[6]); o[7] = fmaf(hv, w1.w, o[7]);
        }
        __half2 hh[4];
#pragma unroll
        for (int k = 0; k < 4; k++)
            hh[k] = __float22half2_rn(make_float2(o[2*k]*dv, o[2*k+1]*dv));
        ((float4*)tout)[(size_t)n*4 + q] = *(float4*)hh;
    }
}

// ===== edge-parallel gather + elu + output MLP + sigmoid col 0 ==============
__global__ __launch_bounds__(256)
void k_gather_out(const __half* __restrict__ tin, const int* __restrict__ ep,
                  const int* __restrict__ bcnt, const float* __restrict__ dis,
                  const float* __restrict__ bg3,
                  const float* __restrict__ wo1, const float* __restrict__ bo1,
                  const float* __restrict__ wo2, const float* __restrict__ bo2,
                  const float* __restrict__ wo3, const float* __restrict__ bo3,
                  float* __restrict__ out, int N){
    __shared__ int iacc[BSZ][HF+1];
    __shared__ float sW1[HF*HF], sW2[HF*HF], sW3[HF*4];
    float* facc = (float*)iacc;
    int t = threadIdx.x, b = blockIdx.x;
    for (int i = t; i < HF*HF; i += 256){ sW1[i] = wo1[i]; sW2[i] = wo2[i]; }
    if (t < HF*4) sW3[t] = wo3[t];
    for (int i = t; i < BSZ*(HF+1); i += 256) ((int*)iacc)[i] = 0;
    int cnt = bcnt[b];
    int base = b*CAP;
    __syncthreads();
    int g = t >> 2, l = t & 3;
    const float4* tv = (const float4*)tin;
    int j = g;
    for (; j + 192 < cnt; j += 256){        // 4 rows in flight per group
        int p0 = ep[base + j];
        int p1 = ep[base + j + 64];
        int p2 = ep[base + j + 128];
        int p3 = ep[base + j + 192];
        float4 r0 = tv[(size_t)(p0 >> BSH)*4 + l];
        float4 r1 = tv[(size_t)(p1 >> BSH)*4 + l];
        float4 r2 = tv[(size_t)(p2 >> BSH)*4 + l];
        float4 r3 = tv[(size_t)(p3 >> BSH)*4 + l];
        accum8_fx(&iacc[p0 & (BSZ-1)][8*l], r0);
        accum8_fx(&iacc[p1 & (BSZ-1)][8*l], r1);
        accum8_fx(&iacc[p2 & (BSZ-1)][8*l], r2);
        accum8_fx(&iacc[p3 & (BSZ-1)][8*l], r3);
    }
    for (; j + 64 < cnt; j += 128){
        int p0 = ep[base + j], p1 = ep[base + j + 64];
        float4 r0 = tv[(size_t)(p0 >> BSH)*4 + l];
        float4 r1 = tv[(size_t)(p1 >> BSH)*4 + l];
        accum8_fx(&iacc[p0 & (BSZ-1)][8*l], r0);
        accum8_fx(&iacc[p1 & (BSZ-1)][8*l], r1);
    }
    for (; j < cnt; j += 64){
        int p0 = ep[base + j];
        float4 r0 = tv[(size_t)(p0 >> BSH)*4 + l];
        accum8_fx(&iacc[p0 & (BSZ-1)][8*l], r0);
    }
    __syncthreads();
    int nloc = t >> 2, q = t & 3;
    int n = b*BSZ + nloc;
    // finish: fx->f32 + self + dis + bg3 + elu -> facc (h for output MLP)
    float fin[8];
    if (n < N){
        float dv = dis[n];
        float4 s0 = tv[(size_t)n*4 + q];
        const __half2* ph = (const __half2*)&s0;
#pragma unroll
        for (int k = 0; k < 4; k++){
            float2 f2 = __half22float2(ph[k]);
            int f = 8*q + 2*k;
            float a0 = (float)iacc[nloc][f]   * FXI + f2.x;
            float a1 = (float)iacc[nloc][f+1] * FXI + f2.y;
            fin[2*k]   = elu1(fmaf(dv, a0, bg3[f]));
            fin[2*k+1] = elu1(fmaf(dv, a1, bg3[f+1]));
        }
    }
    __syncthreads();
    if (n < N){
#pragma unroll
        for (int k = 0; k < 8; k++) facc[nloc*(HF+1) + 8*q + k] = fin[k];
    }
    __syncthreads();
    // o1 = leaky(h @ Wo1 + bo1)
    float o1[8];
    if (n < N){
        int fo = 8*q;
#pragma unroll
        for (int c = 0; c < 8; c++) o1[c] = bo1[fo + c];
#pragma unroll
        for (int i = 0; i < HF; i++){
            float hv = facc[nloc*(HF+1) + i];
            float4 w0 = *(const float4*)&sW1[i*HF + fo];
            float4 w1 = *(const float4*)&sW1[i*HF + fo + 4];
            o1[0] = fmaf(hv, w0.x, o1[0]); o1[1] = fmaf(hv, w0.y, o1[1]);
            o1[2] = fmaf(hv, w0.z, o1[2]); o1[3] = fmaf(hv, w0.w, o1[3]);
            o1[4] = fmaf(hv, w1.x, o1[4]); o1[5] = fmaf(hv, w1.y, o1[5]);
            o1[6] = fmaf(hv, w1.z, o1[6]); o1[7] = fmaf(hv, w1.w, o1[7]);
        }
    }
    __syncthreads();
    if (n < N){
        int fo = 8*q;
#pragma unroll
        for (int c = 0; c < 8; c++) facc[nloc*(HF+1) + fo + c] = leaky(o1[c]);
    }
    __syncthreads();
    // o2 = leaky(o1 @ Wo2 + bo2)
    float o2[8];
    if (n < N){
        int fo = 8*q;
#pragma unroll
        for (int c = 0; c < 8; c++) o2[c] = bo2[fo + c];
#pragma unroll
        for (int i = 0; i < HF; i++){
            float hv = facc[nloc*(HF+1) + i];
            float4 w0 = *(const float4*)&sW2[i*HF + fo];
            float4 w1 = *(const float4*)&sW2[i*HF + fo + 4];
            o2[0] = fmaf(hv, w0.x, o2[0]); o2[1] = fmaf(hv, w0.y, o2[1]);
            o2[2] = fmaf(hv, w0.z, o2[2]); o2[3] = fmaf(hv, w0.w, o2[3]);
            o2[4] = fmaf(hv, w1.x, o2[4]); o2[5] = fmaf(hv, w1.y, o2[5]);
            o2[6] = fmaf(hv, w1.z, o2[6]); o2[7] = fmaf(hv, w1.w, o2[7]);
        }
    }
    __syncthreads();
    if (n < N){
        int fo = 8*q;
#pragma unroll
        for (int c = 0; c < 8; c++) facc[nloc*(HF+1) + fo + c] = leaky(o2[c]);
    }
    __syncthreads();
    // final: 4 threads/node, 1 output each
    if (n < N){
        float v = bo3[q];
#pragma unroll
        for (int i = 0; i < HF; i++) v = fmaf(facc[nloc*(HF+1) + i], sW3[i*4 + q], v);
        if (q == 0) v = sigmoidf(v);
        out[(size_t)n*4 + q] = v;
    }
}

extern "C" void kernel_launch(void* const* d_in, const int* in_sizes, int n_in,
                              void* d_out, int out_size, void* d_ws, size_t ws_size,
                              hipStream_t stream) {
    const float* x     = (const float*)d_in[0];
    const float* w_in1 = (const float*)d_in[1];
    const float* b_in1 = (const float*)d_in[2];
    const float* w_in2 = (const float*)d_in[3];
    const float* b_in2 = (const float*)d_in[4];
    const float* gamma = (const float*)d_in[5];
    const float* beta  = (const float*)d_in[6];
    const float* wg1   = (const float*)d_in[7];
    const float* bg1   = (const float*)d_in[8];
    const float* wg2   = (const float*)d_in[9];
    const float* bg2   = (const float*)d_in[10];
    const float* wg3   = (const float*)d_in[11];
    const float* bg3   = (const float*)d_in[12];
    const float* wo1   = (const float*)d_in[13];
    const float* bo1   = (const float*)d_in[14];
    const float* wo2   = (const float*)d_in[15];
    const float* bo2   = (const float*)d_in[16];
    const float* wo3   = (const float*)d_in[17];
    const float* bo3   = (const float*)d_in[18];
    const int*   ei    = (const int*)d_in[19];

    int N = in_sizes[0] / 3;
    int E = in_sizes[19] / 2;
    int B = (N + BSZ - 1) >> BSH;          // buckets (1563; bin arrays hold 2048)

    char* w = (char*)d_ws;
    size_t o = 0;
    auto alloc = [&](size_t bytes){ size_t r = o; o = (o + bytes + 255) & ~(size_t)255; return r; };
    // ---- zeroed region ----
    float* stats = (float*)(w + alloc(2*HF*sizeof(float)));
    int*   gfill = (int*)  (w + alloc((size_t)B*8*4));
    size_t zero_bytes = o;
    // ---- rest ----
    int*   bcnt  = (int*)  (w + alloc((size_t)B*4));
    float* dis   = (float*)(w + alloc((size_t)N*4));
    int*   ep    = (int*)  (w + alloc((size_t)B*CAP*4));
    int*   ep2   = (int*)  (w + alloc((size_t)B*CAP*4));
    __half* bufH = (__half*)(w + alloc((size_t)N*HF*2));
    __half* tA   = (__half*)(w + alloc((size_t)N*HF*2));
    __half* tB   = (__half*)(w + alloc((size_t)N*HF*2));

    hipMemsetAsync(d_ws, 0, zero_bytes, stream);

    const int* src = ei;
    const int* dst = ei + E;
    int NB1 = (N + 255) / 256;
    int NC  = (E + CH - 1) / CH;

    k_mlp_bin<<<NC + NB1, 256, 0, stream>>>(x, w_in1, b_in1, w_in2, b_in2, bufH, stats,
                                            src, dst, gfill, ep, N, E, B, NC);
    k_deg_t1<<<B, 256, 0, stream>>>(ep, ep2, gfill, bcnt, dis,
                                    bufH, stats, gamma, beta, wg1, tA, N, B);
    k_gather_t<<<B, 256, 0, stream>>>(tA, ep2, bcnt, dis, bg1, wg2, tB, N);
    k_gather_t<<<B, 256, 0, stream>>>(tB, ep2, bcnt, dis, bg2, wg3, tA, N);
    k_gather_out<<<B, 256, 0, stream>>>(tA, ep2, bcnt, dis, bg3,
                                        wo1, bo1, wo2, bo2, wo3, bo3, (float*)d_out, N);
}